// Round 4
// baseline (354.717 us; speedup 1.0000x reference)
//
#include <hip/hip_runtime.h>
#include <math.h>

// GATv2 x2 layers, N=50000, E=600000, D=128.
//  CSR over dst (memset + count + single-block scan + scatter) ->
//  per layer: register-resident-W MFMA GEMM (XL bf16, XR bf16, RES fp32),
//  then per-node online-softmax aggregation:
//  1 wave/node, two 32-lane halves, masked 8-edge batches, packed-f32 math.

#define DIM 128
#define NEG_SLOPE 0.2f
#define TPW 4

typedef __attribute__((ext_vector_type(8))) short short8;
typedef __attribute__((ext_vector_type(4))) float floatx4;
typedef __attribute__((ext_vector_type(2))) float f32x2;

static __device__ __forceinline__ unsigned short f2b(float f) {
    unsigned u = __float_as_uint(f);
    unsigned r = (u + 0x7FFFu + ((u >> 16) & 1u)) >> 16;   // RNE
    return (unsigned short)r;
}
static __device__ __forceinline__ float b2f(unsigned short h) {
    return __uint_as_float(((unsigned)h) << 16);
}
// one u32 holding two bf16 (lo = dim d, hi = dim d+1) -> f32 pair
static __device__ __forceinline__ f32x2 cvt2(unsigned u) {
    f32x2 r;
    r.x = __uint_as_float(u << 16);
    r.y = __uint_as_float(u & 0xffff0000u);
    return r;
}
static __device__ __forceinline__ f32x2 pk_add(f32x2 a, f32x2 b) {
    f32x2 d;
    asm("v_pk_add_f32 %0, %1, %2" : "=v"(d) : "v"(a), "v"(b));
    return d;
}
static __device__ __forceinline__ f32x2 pk_mul(f32x2 a, f32x2 b) {
    f32x2 d;
    asm("v_pk_mul_f32 %0, %1, %2" : "=v"(d) : "v"(a), "v"(b));
    return d;
}
static __device__ __forceinline__ f32x2 pk_fma(f32x2 a, f32x2 b, f32x2 c) {
    f32x2 d;
    asm("v_pk_fma_f32 %0, %1, %2, %3" : "=v"(d) : "v"(a), "v"(b), "v"(c));
    return d;
}
static __device__ __forceinline__ f32x2 pk_abs2(f32x2 a) {
    f32x2 r;
    r.x = __builtin_fabsf(a.x);
    r.y = __builtin_fabsf(a.y);
    return r;
}

// ---------------- CSR build ----------------
__global__ void k_count(const int* __restrict__ dst, int E, int* __restrict__ counts) {
    int k = blockIdx.x * blockDim.x + threadIdx.x;
    if (k < E) atomicAdd(&counts[dst[k]], 1);
}

// single-block scan: counts (without self loop) -> rowptr (+1 per node), cursors in-place
__global__ __launch_bounds__(1024) void k_scan(int* __restrict__ cnt, int n,
                                               int* __restrict__ rowptr) {
    __shared__ int sh[1024];
    int tid = threadIdx.x;
    int chunk = (n + 1023) >> 10;
    int b = tid * chunk;
    int e = min(b + chunk, n);
    int s = 0;
    for (int i = b; i < e; i++) s += cnt[i] + 1;
    sh[tid] = s;
    __syncthreads();
    for (int off = 1; off < 1024; off <<= 1) {
        int t = (tid >= off) ? sh[tid - off] : 0;
        __syncthreads();
        sh[tid] += t;
        __syncthreads();
    }
    int run = sh[tid] - s;   // exclusive prefix of this thread's chunk
    for (int i = b; i < e; i++) {
        int c = cnt[i] + 1;
        cnt[i] = run;        // cursor
        run += c;
        rowptr[i + 1] = run;
    }
    if (tid == 0) rowptr[0] = 0;
}

__global__ void k_scatter(const int* __restrict__ src, const int* __restrict__ dst,
                          int E, int n, int* __restrict__ cur, int* __restrict__ srt) {
    int k = blockIdx.x * blockDim.x + threadIdx.x;
    int tot = E + n;
    if (k >= tot) return;
    int s, d;
    if (k < E) { s = src[k]; d = dst[k]; }
    else       { s = k - E;  d = s; }
    int p = atomicAdd(&cur[d], 1);
    srt[p] = s;
}

// ---------------- fused pre-pass: W fragmentization + H fragmentization ----------------
// blocks [0,48): wfrag[l][sec][ks][nr][lane][j] = bf16( W[ks*32+(lane>>4)*8+j][nr*16+(lane&15)] )
// blocks [48, 48+ntiles): hfrag[tile][ks][lane][j] = bf16( h[tile*16+(lane&15)][ks*32+(lane>>4)*8+j] )
__global__ void k_pre(const float* __restrict__ Wl, const float* __restrict__ Wr,
                      const float* __restrict__ Wres, unsigned short* __restrict__ wfrag,
                      const float* __restrict__ h, unsigned short* __restrict__ hfrag,
                      int n, int ntiles) {
    int blk = blockIdx.x;
    if (blk < 48) {
        int idx = blk * 256 + threadIdx.x;      // < 2*3*4*8*64 = 12288
        int lane = idx & 63;
        int nr   = (idx >> 6) & 7;
        int ks   = (idx >> 9) & 3;
        int v    = idx >> 11;                   // l*3+sec
        int sec = v % 3, l = v / 3;
        const float* W = (sec == 0) ? (Wl + l * DIM * DIM)
                       : (sec == 1) ? (Wr + l * DIM * DIM) : Wres;
        int nn = nr * 16 + (lane & 15);
        int k0 = ks * 32 + ((lane >> 4) << 3);
        ushort4 a, b;
        a.x = f2b(W[(k0 + 0) * DIM + nn]); a.y = f2b(W[(k0 + 1) * DIM + nn]);
        a.z = f2b(W[(k0 + 2) * DIM + nn]); a.w = f2b(W[(k0 + 3) * DIM + nn]);
        b.x = f2b(W[(k0 + 4) * DIM + nn]); b.y = f2b(W[(k0 + 5) * DIM + nn]);
        b.z = f2b(W[(k0 + 6) * DIM + nn]); b.w = f2b(W[(k0 + 7) * DIM + nn]);
        *(ushort4*)(wfrag + (size_t)idx * 8) = a;
        *(ushort4*)(wfrag + (size_t)idx * 8 + 4) = b;
    } else {
        int idx = (blk - 48) * 256 + threadIdx.x;
        if (idx >= ntiles * 256) return;
        int lane = idx & 63;
        int ks   = (idx >> 6) & 3;
        int tile = idx >> 8;
        int row  = tile * 16 + (lane & 15);
        int col0 = ks * 32 + ((lane >> 4) << 3);
        ushort4 a = {0, 0, 0, 0}, b = {0, 0, 0, 0};
        if (row < n) {
            float4 v0 = *(const float4*)(h + (size_t)row * DIM + col0);
            float4 v1 = *(const float4*)(h + (size_t)row * DIM + col0 + 4);
            a.x = f2b(v0.x); a.y = f2b(v0.y); a.z = f2b(v0.z); a.w = f2b(v0.w);
            b.x = f2b(v1.x); b.y = f2b(v1.y); b.z = f2b(v1.z); b.w = f2b(v1.w);
        }
        *(ushort4*)(hfrag + (size_t)idx * 8) = a;
        *(ushort4*)(hfrag + (size_t)idx * 8 + 4) = b;
    }
}

// ---------------- register-resident-W MFMA GEMM ----------------
__global__ __launch_bounds__(256, 2) void k_gemm(
    const unsigned short* __restrict__ hfrag, const unsigned short* __restrict__ wfrag,
    const float* __restrict__ bl, const float* __restrict__ br, const float* __restrict__ bres,
    unsigned short* __restrict__ XLb, unsigned short* __restrict__ XRb,
    float* __restrict__ RES, int ntiles)
{
    int sec  = blockIdx.y;
    int lane = threadIdx.x & 63;
    int w    = threadIdx.x >> 6;

    const unsigned short* wbase = wfrag + (size_t)sec * (4 * 8 * 64 * 8);
    short8 bf[4][8];
#pragma unroll
    for (int ks = 0; ks < 4; ks++)
#pragma unroll
        for (int nr = 0; nr < 8; nr++)
            bf[ks][nr] = *(const short8*)(wbase + (((ks * 8 + nr) * 64 + lane) << 3));

    const float* bias = (sec == 0) ? bl : (sec == 1) ? br : bres;
    int colb = (lane >> 4) << 2;
    float4 bv[8];
#pragma unroll
    for (int nr = 0; nr < 8; nr++) bv[nr] = *(const float4*)(bias + nr * 16 + colb);

    int wid = blockIdx.x * 4 + w;
#pragma unroll
    for (int i = 0; i < TPW; i++) {
        int t = wid * TPW + i;
        if (t >= ntiles) break;
        short8 a[4];
#pragma unroll
        for (int ks = 0; ks < 4; ks++)
            a[ks] = *(const short8*)(hfrag + (((t * 4 + ks) * 64 + lane) << 3));
        floatx4 acc[8];
#pragma unroll
        for (int nr = 0; nr < 8; nr++) acc[nr] = (floatx4){0.f, 0.f, 0.f, 0.f};
#pragma unroll
        for (int ks = 0; ks < 4; ks++)
#pragma unroll
            for (int nr = 0; nr < 8; nr++)
                acc[nr] = __builtin_amdgcn_mfma_f32_16x16x32_bf16(bf[ks][nr], a[ks], acc[nr], 0, 0, 0);

        int row = t * 16 + (lane & 15);
        size_t rb = (size_t)row * DIM;
#pragma unroll
        for (int nr = 0; nr < 8; nr++) {
            float4 o;
            o.x = acc[nr][0] + bv[nr].x;
            o.y = acc[nr][1] + bv[nr].y;
            o.z = acc[nr][2] + bv[nr].z;
            o.w = acc[nr][3] + bv[nr].w;
            int col = nr * 16 + colb;
            if (sec == 2) {
                *(float4*)(RES + rb + col) = o;
            } else {
                ushort4 u;
                u.x = f2b(o.x); u.y = f2b(o.y); u.z = f2b(o.z); u.w = f2b(o.w);
                if (sec == 0) *(ushort4*)(XLb + rb + col) = u;
                else          *(ushort4*)(XRb + rb + col) = u;
            }
        }
    }
}

// ---------------- aggregation ----------------
#define EDGE_LOGIT(K, JOFF)                                              \
    f32x2 v01_##K = cvt2(e##K.x), v23_##K = cvt2(e##K.y);                \
    f32x2 t01_##K = pk_add(v01_##K, x01);                                \
    f32x2 t23_##K = pk_add(v23_##K, x23);                                \
    f32x2 pp_##K = pk_mul(a6_01, t01_##K);                               \
    pp_##K = pk_fma(a4_01, pk_abs2(t01_##K), pp_##K);                    \
    pp_##K = pk_fma(a6_23, t23_##K, pp_##K);                             \
    pp_##K = pk_fma(a4_23, pk_abs2(t23_##K), pp_##K);                    \
    float p##K = pp_##K.x + pp_##K.y;                                    \
    p##K = (j + JOFF < se) ? p##K : -3.0e38f;

__global__ __launch_bounds__(256) void k_aggr(
    const unsigned short* __restrict__ XLb, const unsigned short* __restrict__ XRb,
    const float* __restrict__ RES, const float* __restrict__ att,
    const float* __restrict__ bias, const int* __restrict__ rowptr,
    const int* __restrict__ srt, float* __restrict__ outF,
    unsigned short* __restrict__ fragOut, int writeFrag, int n)
{
    int wave = threadIdx.x >> 6;
    int lane = threadIdx.x & 63;
    int node = blockIdx.x * 4 + wave;
    if (node >= n) return;
    int half = lane >> 5, sl = lane & 31;
    int d0 = sl << 2;

    float a0 = att[d0], a1 = att[d0 + 1], a2 = att[d0 + 2], a3 = att[d0 + 3];
    f32x2 a6_01 = {0.6f * a0, 0.6f * a1}, a6_23 = {0.6f * a2, 0.6f * a3};
    f32x2 a4_01 = {0.4f * a0, 0.4f * a1}, a4_23 = {0.4f * a2, 0.4f * a3};

    uint2 xru = *(const uint2*)(XRb + (size_t)node * DIM + d0);
    f32x2 x01 = cvt2(xru.x), x23 = cvt2(xru.y);

    int beg = rowptr[node], end = rowptr[node + 1];
    int len = end - beg;
    int hl = (len + 1) >> 1;
    int sb = beg + half * hl;
    int se = half ? end : (beg + hl);

    const uint2* R = (const uint2*)XLb;   // row i at R[i*32 + sl]

    float m = -INFINITY, den = 0.f;
    float ax = 0.f, ay = 0.f, az = 0.f, aw = 0.f;

    for (int j = sb; j < se; j += 8) {
        int4 sA = *(const int4*)(srt + j);
        int4 sB = *(const int4*)(srt + j + 4);
        int i0 = sA.x;
        int i1 = (j + 1 < se) ? sA.y : i0;
        int i2 = (j + 2 < se) ? sA.z : i0;
        int i3 = (j + 3 < se) ? sA.w : i0;
        int i4 = (j + 4 < se) ? sB.x : i0;
        int i5 = (j + 5 < se) ? sB.y : i0;
        int i6 = (j + 6 < se) ? sB.z : i0;
        int i7 = (j + 7 < se) ? sB.w : i0;
        uint2 e0 = R[(size_t)i0 * 32 + sl];
        uint2 e1 = R[(size_t)i1 * 32 + sl];
        uint2 e2 = R[(size_t)i2 * 32 + sl];
        uint2 e3 = R[(size_t)i3 * 32 + sl];
        uint2 e4 = R[(size_t)i4 * 32 + sl];
        uint2 e5 = R[(size_t)i5 * 32 + sl];
        uint2 e6 = R[(size_t)i6 * 32 + sl];
        uint2 e7 = R[(size_t)i7 * 32 + sl];
        EDGE_LOGIT(0, 0) EDGE_LOGIT(1, 1) EDGE_LOGIT(2, 2) EDGE_LOGIT(3, 3)
        EDGE_LOGIT(4, 4) EDGE_LOGIT(5, 5) EDGE_LOGIT(6, 6) EDGE_LOGIT(7, 7)
#pragma unroll
        for (int off = 16; off >= 1; off >>= 1) {
            p0 += __shfl_xor(p0, off); p1 += __shfl_xor(p1, off);
            p2 += __shfl_xor(p2, off); p3 += __shfl_xor(p3, off);
            p4 += __shfl_xor(p4, off); p5 += __shfl_xor(p5, off);
            p6 += __shfl_xor(p6, off); p7 += __shfl_xor(p7, off);
        }
        float pm = fmaxf(fmaxf(fmaxf(p0, p1), fmaxf(p2, p3)),
                         fmaxf(fmaxf(p4, p5), fmaxf(p6, p7)));
        float mn = fmaxf(m, pm);
        float c  = __expf(m - mn);
        float w0 = __expf(p0 - mn), w1 = __expf(p1 - mn);
        float w2 = __expf(p2 - mn), w3 = __expf(p3 - mn);
        float w4 = __expf(p4 - mn), w5 = __expf(p5 - mn);
        float w6 = __expf(p6 - mn), w7 = __expf(p7 - mn);
        ax = ax * c + w0 * v01_0.x + w1 * v01_1.x + w2 * v01_2.x + w3 * v01_3.x
                    + w4 * v01_4.x + w5 * v01_5.x + w6 * v01_6.x + w7 * v01_7.x;
        ay = ay * c + w0 * v01_0.y + w1 * v01_1.y + w2 * v01_2.y + w3 * v01_3.y
                    + w4 * v01_4.y + w5 * v01_5.y + w6 * v01_6.y + w7 * v01_7.y;
        az = az * c + w0 * v23_0.x + w1 * v23_1.x + w2 * v23_2.x + w3 * v23_3.x
                    + w4 * v23_4.x + w5 * v23_5.x + w6 * v23_6.x + w7 * v23_7.x;
        aw = aw * c + w0 * v23_0.y + w1 * v23_1.y + w2 * v23_2.y + w3 * v23_3.y
                    + w4 * v23_4.y + w5 * v23_5.y + w6 * v23_6.y + w7 * v23_7.y;
        den = den * c + (((w0 + w1) + (w2 + w3)) + ((w4 + w5) + (w6 + w7)));
        m = mn;
    }

    // merge the two half-wave online softmaxes
    float om   = __shfl_xor(m, 32);
    float oden = __shfl_xor(den, 32);
    float ox = __shfl_xor(ax, 32), oy = __shfl_xor(ay, 32);
    float oz = __shfl_xor(az, 32), ow = __shfl_xor(aw, 32);
    float M  = fmaxf(m, om);
    float se_ = __expf(m - M), so = __expf(om - M);
    float D  = den * se_ + oden * so + 1e-16f;
    float inv = 1.f / D;

    float4 r4 = *(const float4*)(RES + (size_t)node * DIM + d0);
    float4 b4 = *(const float4*)(bias + d0);
    float4 o;
    o.x = fmaxf((ax * se_ + ox * so) * inv + b4.x + r4.x, 0.f);
    o.y = fmaxf((ay * se_ + oy * so) * inv + b4.y + r4.y, 0.f);
    o.z = fmaxf((az * se_ + oz * so) * inv + b4.z + r4.z, 0.f);
    o.w = fmaxf((aw * se_ + ow * so) * inv + b4.w + r4.w, 0.f);

    if (half == 0) {
        if (writeFrag) {
            int tile = node >> 4;
            int ks = sl >> 3;
            int li = (node & 15) + (((sl >> 1) & 3) << 4);
            int j0 = (sl & 1) << 2;
            ushort4 u;
            u.x = f2b(o.x); u.y = f2b(o.y); u.z = f2b(o.z); u.w = f2b(o.w);
            *(ushort4*)(fragOut + ((size_t)((tile * 4 + ks) * 64 + li) << 3) + j0) = u;
        } else {
            *(float4*)(outF + (size_t)node * DIM + d0) = o;
        }
    }
}

extern "C" void kernel_launch(void* const* d_in, const int* in_sizes, int n_in,
                              void* d_out, int out_size, void* d_ws, size_t ws_size,
                              hipStream_t stream) {
    const float* x    = (const float*)d_in[0];
    const int*   ei   = (const int*)d_in[1];
    const float* Wl   = (const float*)d_in[2];
    const float* bl   = (const float*)d_in[3];
    const float* Wr   = (const float*)d_in[4];
    const float* br   = (const float*)d_in[5];
    const float* att  = (const float*)d_in[6];
    const float* bias = (const float*)d_in[7];
    const float* Wres = (const float*)d_in[8];
    const float* bres = (const float*)d_in[9];

    int n = in_sizes[0] / DIM;
    int E = in_sizes[1] / 2;
    int ntiles = (n + 15) >> 4;
    const int* srcIdx = ei;
    const int* dstIdx = ei + E;

    // workspace layout
    float* resb = (float*)d_ws;
    unsigned short* xlb   = (unsigned short*)(resb + (size_t)n * DIM);
    unsigned short* xrb   = xlb + (size_t)n * DIM;
    unsigned short* hfrag = xrb + (size_t)n * DIM;
    unsigned short* wfrag = hfrag + (size_t)ntiles * 16 * DIM;
    int* rowptr = (int*)(wfrag + 2 * 3 * DIM * DIM);
    int* tmpc   = rowptr + (n + 1);
    int* srt    = tmpc + n;                 // E+n used, +8 pad

    hipMemsetAsync(tmpc, 0, (size_t)n * sizeof(int), stream);
    k_count<<<(E + 255) / 256, 256, 0, stream>>>(dstIdx, E, tmpc);
    k_pre<<<48 + ntiles, 256, 0, stream>>>(Wl, Wr, Wres, wfrag, x, hfrag, n, ntiles);
    k_scan<<<1, 1024, 0, stream>>>(tmpc, n, rowptr);
    k_scatter<<<(E + n + 255) / 256, 256, 0, stream>>>(srcIdx, dstIdx, E, n, tmpc, srt);

    int gx = (ntiles + 4 * TPW - 1) / (4 * TPW);
    for (int l = 0; l < 2; l++) {
        dim3 g(gx, 3);
        k_gemm<<<g, 256, 0, stream>>>(hfrag, wfrag + (size_t)l * 3 * 4 * 8 * 64 * 8,
                                      bl + (size_t)l * DIM, br + (size_t)l * DIM, bres,
                                      xlb, xrb, resb, ntiles);
        k_aggr<<<(n + 3) / 4, 256, 0, stream>>>(xlb, xrb, resb, att + (size_t)l * DIM,
                                                bias + (size_t)l * DIM, rowptr, srt,
                                                (float*)d_out, hfrag, (l == 0) ? 1 : 0, n);
    }
}

// Round 5
// 242.030 us; speedup vs baseline: 1.4656x; 1.4656x over previous
//
#include <hip/hip_runtime.h>
#include <math.h>

// GATv2 x2 layers, N=50000, E=600000, D=128.
//  CSR over dst (init=1 + atomic count + hierarchical 3-kernel scan + scatter) ->
//  per layer: register-resident-W MFMA GEMM (XL bf16, XR bf16, RES fp32),
//  then per-node online-softmax aggregation:
//  1 wave/node, two 32-lane halves, masked 8-edge batches, packed-f32 math.

#define DIM 128
#define NEG_SLOPE 0.2f
#define TPW 4

typedef __attribute__((ext_vector_type(8))) short short8;
typedef __attribute__((ext_vector_type(4))) float floatx4;
typedef __attribute__((ext_vector_type(2))) float f32x2;

static __device__ __forceinline__ unsigned short f2b(float f) {
    unsigned u = __float_as_uint(f);
    unsigned r = (u + 0x7FFFu + ((u >> 16) & 1u)) >> 16;   // RNE
    return (unsigned short)r;
}
// one u32 holding two bf16 (lo = dim d, hi = dim d+1) -> f32 pair
static __device__ __forceinline__ f32x2 cvt2(unsigned u) {
    f32x2 r;
    r.x = __uint_as_float(u << 16);
    r.y = __uint_as_float(u & 0xffff0000u);
    return r;
}
static __device__ __forceinline__ f32x2 pk_add(f32x2 a, f32x2 b) {
    f32x2 d;
    asm("v_pk_add_f32 %0, %1, %2" : "=v"(d) : "v"(a), "v"(b));
    return d;
}
static __device__ __forceinline__ f32x2 pk_mul(f32x2 a, f32x2 b) {
    f32x2 d;
    asm("v_pk_mul_f32 %0, %1, %2" : "=v"(d) : "v"(a), "v"(b));
    return d;
}
static __device__ __forceinline__ f32x2 pk_fma(f32x2 a, f32x2 b, f32x2 c) {
    f32x2 d;
    asm("v_pk_fma_f32 %0, %1, %2, %3" : "=v"(d) : "v"(a), "v"(b), "v"(c));
    return d;
}
static __device__ __forceinline__ f32x2 pk_abs2(f32x2 a) {
    f32x2 r;
    r.x = __builtin_fabsf(a.x);
    r.y = __builtin_fabsf(a.y);
    return r;
}

// ---------------- CSR build (hierarchical scan, all multi-block) ----------------
__global__ void k_init_counts(int* __restrict__ counts, int n) {
    int i = blockIdx.x * blockDim.x + threadIdx.x;
    if (i < n) counts[i] = 1;  // self loop
}

__global__ void k_count(const int* __restrict__ dst, int E, int* __restrict__ counts) {
    int k = blockIdx.x * blockDim.x + threadIdx.x;
    if (k < E) atomicAdd(&counts[dst[k]], 1);
}

// inclusive scan of counts within 256-blocks -> rowptr[i+1], block totals -> bsum
__global__ void k_scan1(const int* __restrict__ counts, int n,
                        int* __restrict__ rowptr, int* __restrict__ bsum) {
    __shared__ int s[256];
    int tid = threadIdx.x;
    int i = blockIdx.x * 256 + tid;
    int v = (i < n) ? counts[i] : 0;
    s[tid] = v;
    __syncthreads();
    for (int off = 1; off < 256; off <<= 1) {
        int t = (tid >= off) ? s[tid - off] : 0;
        __syncthreads();
        s[tid] += t;
        __syncthreads();
    }
    if (i < n) rowptr[i + 1] = s[tid];
    if (tid == 255) bsum[blockIdx.x] = s[255];
}

// single-block inclusive scan of block sums (nb <= 256; n=50000 -> nb=196)
__global__ void k_scan2(int* __restrict__ bsum, int nb) {
    __shared__ int s[256];
    int tid = threadIdx.x;
    int v = (tid < nb) ? bsum[tid] : 0;
    s[tid] = v;
    __syncthreads();
    for (int off = 1; off < 256; off <<= 1) {
        int t = (tid >= off) ? s[tid - off] : 0;
        __syncthreads();
        s[tid] += t;
        __syncthreads();
    }
    if (tid < nb) bsum[tid] = s[tid];
}

// add block offsets; rowptr[0]=0; cursors[i] = exclusive prefix (in counts buffer)
__global__ void k_scan3(int* __restrict__ rowptr, const int* __restrict__ bsum,
                        int n, int* __restrict__ counts_to_cursors) {
    int i = blockIdx.x * 256 + threadIdx.x;
    if (i < n) {
        int add = (blockIdx.x > 0) ? bsum[blockIdx.x - 1] : 0;
        int cnt = counts_to_cursors[i];
        int v = rowptr[i + 1] + add;
        rowptr[i + 1] = v;
        counts_to_cursors[i] = v - cnt;  // cursor = exclusive prefix
    }
    if (i == 0) rowptr[0] = 0;
}

__global__ void k_scatter(const int* __restrict__ src, const int* __restrict__ dst,
                          int E, int n, int* __restrict__ cur, int* __restrict__ srt) {
    int k = blockIdx.x * blockDim.x + threadIdx.x;
    int tot = E + n;
    if (k >= tot) return;
    int s, d;
    if (k < E) { s = src[k]; d = dst[k]; }
    else       { s = k - E;  d = s; }
    int p = atomicAdd(&cur[d], 1);
    srt[p] = s;
}

// ---------------- fused pre-pass: W fragmentization + H fragmentization ----------------
__global__ void k_pre(const float* __restrict__ Wl, const float* __restrict__ Wr,
                      const float* __restrict__ Wres, unsigned short* __restrict__ wfrag,
                      const float* __restrict__ h, unsigned short* __restrict__ hfrag,
                      int n, int ntiles) {
    int blk = blockIdx.x;
    if (blk < 48) {
        int idx = blk * 256 + threadIdx.x;      // < 2*3*4*8*64 = 12288
        int lane = idx & 63;
        int nr   = (idx >> 6) & 7;
        int ks   = (idx >> 9) & 3;
        int v    = idx >> 11;                   // l*3+sec
        int sec = v % 3, l = v / 3;
        const float* W = (sec == 0) ? (Wl + l * DIM * DIM)
                       : (sec == 1) ? (Wr + l * DIM * DIM) : Wres;
        int nn = nr * 16 + (lane & 15);
        int k0 = ks * 32 + ((lane >> 4) << 3);
        ushort4 a, b;
        a.x = f2b(W[(k0 + 0) * DIM + nn]); a.y = f2b(W[(k0 + 1) * DIM + nn]);
        a.z = f2b(W[(k0 + 2) * DIM + nn]); a.w = f2b(W[(k0 + 3) * DIM + nn]);
        b.x = f2b(W[(k0 + 4) * DIM + nn]); b.y = f2b(W[(k0 + 5) * DIM + nn]);
        b.z = f2b(W[(k0 + 6) * DIM + nn]); b.w = f2b(W[(k0 + 7) * DIM + nn]);
        *(ushort4*)(wfrag + (size_t)idx * 8) = a;
        *(ushort4*)(wfrag + (size_t)idx * 8 + 4) = b;
    } else {
        int idx = (blk - 48) * 256 + threadIdx.x;
        if (idx >= ntiles * 256) return;
        int lane = idx & 63;
        int ks   = (idx >> 6) & 3;
        int tile = idx >> 8;
        int row  = tile * 16 + (lane & 15);
        int col0 = ks * 32 + ((lane >> 4) << 3);
        ushort4 a = {0, 0, 0, 0}, b = {0, 0, 0, 0};
        if (row < n) {
            float4 v0 = *(const float4*)(h + (size_t)row * DIM + col0);
            float4 v1 = *(const float4*)(h + (size_t)row * DIM + col0 + 4);
            a.x = f2b(v0.x); a.y = f2b(v0.y); a.z = f2b(v0.z); a.w = f2b(v0.w);
            b.x = f2b(v1.x); b.y = f2b(v1.y); b.z = f2b(v1.z); b.w = f2b(v1.w);
        }
        *(ushort4*)(hfrag + (size_t)idx * 8) = a;
        *(ushort4*)(hfrag + (size_t)idx * 8 + 4) = b;
    }
}

// ---------------- register-resident-W MFMA GEMM ----------------
__global__ __launch_bounds__(256, 2) void k_gemm(
    const unsigned short* __restrict__ hfrag, const unsigned short* __restrict__ wfrag,
    const float* __restrict__ bl, const float* __restrict__ br, const float* __restrict__ bres,
    unsigned short* __restrict__ XLb, unsigned short* __restrict__ XRb,
    float* __restrict__ RES, int ntiles)
{
    int sec  = blockIdx.y;
    int lane = threadIdx.x & 63;
    int w    = threadIdx.x >> 6;

    const unsigned short* wbase = wfrag + (size_t)sec * (4 * 8 * 64 * 8);
    short8 bf[4][8];
#pragma unroll
    for (int ks = 0; ks < 4; ks++)
#pragma unroll
        for (int nr = 0; nr < 8; nr++)
            bf[ks][nr] = *(const short8*)(wbase + (((ks * 8 + nr) * 64 + lane) << 3));

    const float* bias = (sec == 0) ? bl : (sec == 1) ? br : bres;
    int colb = (lane >> 4) << 2;
    float4 bv[8];
#pragma unroll
    for (int nr = 0; nr < 8; nr++) bv[nr] = *(const float4*)(bias + nr * 16 + colb);

    int wid = blockIdx.x * 4 + w;
#pragma unroll
    for (int i = 0; i < TPW; i++) {
        int t = wid * TPW + i;
        if (t >= ntiles) break;
        short8 a[4];
#pragma unroll
        for (int ks = 0; ks < 4; ks++)
            a[ks] = *(const short8*)(hfrag + (((t * 4 + ks) * 64 + lane) << 3));
        floatx4 acc[8];
#pragma unroll
        for (int nr = 0; nr < 8; nr++) acc[nr] = (floatx4){0.f, 0.f, 0.f, 0.f};
#pragma unroll
        for (int ks = 0; ks < 4; ks++)
#pragma unroll
            for (int nr = 0; nr < 8; nr++)
                acc[nr] = __builtin_amdgcn_mfma_f32_16x16x32_bf16(bf[ks][nr], a[ks], acc[nr], 0, 0, 0);

        int row = t * 16 + (lane & 15);
        size_t rb = (size_t)row * DIM;
#pragma unroll
        for (int nr = 0; nr < 8; nr++) {
            float4 o;
            o.x = acc[nr][0] + bv[nr].x;
            o.y = acc[nr][1] + bv[nr].y;
            o.z = acc[nr][2] + bv[nr].z;
            o.w = acc[nr][3] + bv[nr].w;
            int col = nr * 16 + colb;
            if (sec == 2) {
                *(float4*)(RES + rb + col) = o;
            } else {
                ushort4 u;
                u.x = f2b(o.x); u.y = f2b(o.y); u.z = f2b(o.z); u.w = f2b(o.w);
                if (sec == 0) *(ushort4*)(XLb + rb + col) = u;
                else          *(ushort4*)(XRb + rb + col) = u;
            }
        }
    }
}

// ---------------- aggregation ----------------
#define EDGE_LOGIT(K, JOFF)                                              \
    f32x2 v01_##K = cvt2(e##K.x), v23_##K = cvt2(e##K.y);                \
    f32x2 t01_##K = pk_add(v01_##K, x01);                                \
    f32x2 t23_##K = pk_add(v23_##K, x23);                                \
    f32x2 pp_##K = pk_mul(a6_01, t01_##K);                               \
    pp_##K = pk_fma(a4_01, pk_abs2(t01_##K), pp_##K);                    \
    pp_##K = pk_fma(a6_23, t23_##K, pp_##K);                             \
    pp_##K = pk_fma(a4_23, pk_abs2(t23_##K), pp_##K);                    \
    float p##K = pp_##K.x + pp_##K.y;                                    \
    p##K = (j + JOFF < se) ? p##K : -3.0e38f;

__global__ __launch_bounds__(256) void k_aggr(
    const unsigned short* __restrict__ XLb, const unsigned short* __restrict__ XRb,
    const float* __restrict__ RES, const float* __restrict__ att,
    const float* __restrict__ bias, const int* __restrict__ rowptr,
    const int* __restrict__ srt, float* __restrict__ outF,
    unsigned short* __restrict__ fragOut, int writeFrag, int n)
{
    int wave = threadIdx.x >> 6;
    int lane = threadIdx.x & 63;
    int node = blockIdx.x * 4 + wave;
    if (node >= n) return;
    int half = lane >> 5, sl = lane & 31;
    int d0 = sl << 2;

    float a0 = att[d0], a1 = att[d0 + 1], a2 = att[d0 + 2], a3 = att[d0 + 3];
    f32x2 a6_01 = {0.6f * a0, 0.6f * a1}, a6_23 = {0.6f * a2, 0.6f * a3};
    f32x2 a4_01 = {0.4f * a0, 0.4f * a1}, a4_23 = {0.4f * a2, 0.4f * a3};

    uint2 xru = *(const uint2*)(XRb + (size_t)node * DIM + d0);
    f32x2 x01 = cvt2(xru.x), x23 = cvt2(xru.y);

    int beg = rowptr[node], end = rowptr[node + 1];
    int len = end - beg;
    int hl = (len + 1) >> 1;
    int sb = beg + half * hl;
    int se = half ? end : (beg + hl);

    const uint2* R = (const uint2*)XLb;   // row i at R[i*32 + sl]

    float m = -INFINITY, den = 0.f;
    float ax = 0.f, ay = 0.f, az = 0.f, aw = 0.f;

    for (int j = sb; j < se; j += 8) {
        int4 sA = *(const int4*)(srt + j);
        int4 sB = *(const int4*)(srt + j + 4);
        int i0 = sA.x;
        int i1 = (j + 1 < se) ? sA.y : i0;
        int i2 = (j + 2 < se) ? sA.z : i0;
        int i3 = (j + 3 < se) ? sA.w : i0;
        int i4 = (j + 4 < se) ? sB.x : i0;
        int i5 = (j + 5 < se) ? sB.y : i0;
        int i6 = (j + 6 < se) ? sB.z : i0;
        int i7 = (j + 7 < se) ? sB.w : i0;
        uint2 e0 = R[(size_t)i0 * 32 + sl];
        uint2 e1 = R[(size_t)i1 * 32 + sl];
        uint2 e2 = R[(size_t)i2 * 32 + sl];
        uint2 e3 = R[(size_t)i3 * 32 + sl];
        uint2 e4 = R[(size_t)i4 * 32 + sl];
        uint2 e5 = R[(size_t)i5 * 32 + sl];
        uint2 e6 = R[(size_t)i6 * 32 + sl];
        uint2 e7 = R[(size_t)i7 * 32 + sl];
        EDGE_LOGIT(0, 0) EDGE_LOGIT(1, 1) EDGE_LOGIT(2, 2) EDGE_LOGIT(3, 3)
        EDGE_LOGIT(4, 4) EDGE_LOGIT(5, 5) EDGE_LOGIT(6, 6) EDGE_LOGIT(7, 7)
#pragma unroll
        for (int off = 16; off >= 1; off >>= 1) {
            p0 += __shfl_xor(p0, off); p1 += __shfl_xor(p1, off);
            p2 += __shfl_xor(p2, off); p3 += __shfl_xor(p3, off);
            p4 += __shfl_xor(p4, off); p5 += __shfl_xor(p5, off);
            p6 += __shfl_xor(p6, off); p7 += __shfl_xor(p7, off);
        }
        float pm = fmaxf(fmaxf(fmaxf(p0, p1), fmaxf(p2, p3)),
                         fmaxf(fmaxf(p4, p5), fmaxf(p6, p7)));
        float mn = fmaxf(m, pm);
        float c  = __expf(m - mn);
        float w0 = __expf(p0 - mn), w1 = __expf(p1 - mn);
        float w2 = __expf(p2 - mn), w3 = __expf(p3 - mn);
        float w4 = __expf(p4 - mn), w5 = __expf(p5 - mn);
        float w6 = __expf(p6 - mn), w7 = __expf(p7 - mn);
        ax = ax * c + w0 * v01_0.x + w1 * v01_1.x + w2 * v01_2.x + w3 * v01_3.x
                    + w4 * v01_4.x + w5 * v01_5.x + w6 * v01_6.x + w7 * v01_7.x;
        ay = ay * c + w0 * v01_0.y + w1 * v01_1.y + w2 * v01_2.y + w3 * v01_3.y
                    + w4 * v01_4.y + w5 * v01_5.y + w6 * v01_6.y + w7 * v01_7.y;
        az = az * c + w0 * v23_0.x + w1 * v23_1.x + w2 * v23_2.x + w3 * v23_3.x
                    + w4 * v23_4.x + w5 * v23_5.x + w6 * v23_6.x + w7 * v23_7.x;
        aw = aw * c + w0 * v23_0.y + w1 * v23_1.y + w2 * v23_2.y + w3 * v23_3.y
                    + w4 * v23_4.y + w5 * v23_5.y + w6 * v23_6.y + w7 * v23_7.y;
        den = den * c + (((w0 + w1) + (w2 + w3)) + ((w4 + w5) + (w6 + w7)));
        m = mn;
    }

    // merge the two half-wave online softmaxes
    float om   = __shfl_xor(m, 32);
    float oden = __shfl_xor(den, 32);
    float ox = __shfl_xor(ax, 32), oy = __shfl_xor(ay, 32);
    float oz = __shfl_xor(az, 32), ow = __shfl_xor(aw, 32);
    float M  = fmaxf(m, om);
    float se_ = __expf(m - M), so = __expf(om - M);
    float D  = den * se_ + oden * so + 1e-16f;
    float inv = 1.f / D;

    float4 r4 = *(const float4*)(RES + (size_t)node * DIM + d0);
    float4 b4 = *(const float4*)(bias + d0);
    float4 o;
    o.x = fmaxf((ax * se_ + ox * so) * inv + b4.x + r4.x, 0.f);
    o.y = fmaxf((ay * se_ + oy * so) * inv + b4.y + r4.y, 0.f);
    o.z = fmaxf((az * se_ + oz * so) * inv + b4.z + r4.z, 0.f);
    o.w = fmaxf((aw * se_ + ow * so) * inv + b4.w + r4.w, 0.f);

    if (half == 0) {
        if (writeFrag) {
            int tile = node >> 4;
            int ks = sl >> 3;
            int li = (node & 15) + (((sl >> 1) & 3) << 4);
            int j0 = (sl & 1) << 2;
            ushort4 u;
            u.x = f2b(o.x); u.y = f2b(o.y); u.z = f2b(o.z); u.w = f2b(o.w);
            *(ushort4*)(fragOut + ((size_t)((tile * 4 + ks) * 64 + li) << 3) + j0) = u;
        } else {
            *(float4*)(outF + (size_t)node * DIM + d0) = o;
        }
    }
}

extern "C" void kernel_launch(void* const* d_in, const int* in_sizes, int n_in,
                              void* d_out, int out_size, void* d_ws, size_t ws_size,
                              hipStream_t stream) {
    const float* x    = (const float*)d_in[0];
    const int*   ei   = (const int*)d_in[1];
    const float* Wl   = (const float*)d_in[2];
    const float* bl   = (const float*)d_in[3];
    const float* Wr   = (const float*)d_in[4];
    const float* br   = (const float*)d_in[5];
    const float* att  = (const float*)d_in[6];
    const float* bias = (const float*)d_in[7];
    const float* Wres = (const float*)d_in[8];
    const float* bres = (const float*)d_in[9];

    int n = in_sizes[0] / DIM;
    int E = in_sizes[1] / 2;
    int ntiles = (n + 15) >> 4;
    const int* srcIdx = ei;
    const int* dstIdx = ei + E;

    // workspace layout
    float* resb = (float*)d_ws;
    unsigned short* xlb   = (unsigned short*)(resb + (size_t)n * DIM);
    unsigned short* xrb   = xlb + (size_t)n * DIM;
    unsigned short* hfrag = xrb + (size_t)n * DIM;
    unsigned short* wfrag = hfrag + (size_t)ntiles * 16 * DIM;
    int* rowptr = (int*)(wfrag + 2 * 3 * DIM * DIM);
    int* tmpc   = rowptr + (n + 1);
    int* srt    = tmpc + n;                 // E+n used, +8 pad
    int* bsum   = srt + (E + n + 8);

    int nb1 = (n + 255) / 256;   // 196 <= 256

    k_pre<<<48 + ntiles, 256, 0, stream>>>(Wl, Wr, Wres, wfrag, x, hfrag, n, ntiles);
    k_init_counts<<<nb1, 256, 0, stream>>>(tmpc, n);
    k_count<<<(E + 255) / 256, 256, 0, stream>>>(dstIdx, E, tmpc);
    k_scan1<<<nb1, 256, 0, stream>>>(tmpc, n, rowptr, bsum);
    k_scan2<<<1, 256, 0, stream>>>(bsum, nb1);
    k_scan3<<<nb1, 256, 0, stream>>>(rowptr, bsum, n, tmpc);
    k_scatter<<<(E + n + 255) / 256, 256, 0, stream>>>(srcIdx, dstIdx, E, n, tmpc, srt);

    int gx = (ntiles + 4 * TPW - 1) / (4 * TPW);
    for (int l = 0; l < 2; l++) {
        dim3 g(gx, 3);
        k_gemm<<<g, 256, 0, stream>>>(hfrag, wfrag + (size_t)l * 3 * 4 * 8 * 64 * 8,
                                      bl + (size_t)l * DIM, br + (size_t)l * DIM, bres,
                                      xlb, xrb, resb, ntiles);
        k_aggr<<<(n + 3) / 4, 256, 0, stream>>>(xlb, xrb, resb, att + (size_t)l * DIM,
                                                bias + (size_t)l * DIM, rowptr, srt,
                                                (float*)d_out, hfrag, (l == 0) ? 1 : 0, n);
    }
}